// Round 13
// baseline (230.798 us; speedup 1.0000x reference)
//
#include <hip/hip_runtime.h>
#include <hip/hip_bf16.h>
#include <math.h>

#define BB 2
#define NN 8192
#define DD 512
#define HH 8
#define DK 64
#define KNB 32
#define BN (BB*NN)          // 16384 rows
#define BHN (BB*HH*NN)      // 131072 (b,h,n) tuples

typedef __attribute__((ext_vector_type(8))) _Float16 f16x8;   // 8 f16 in 4 VGPRs
typedef __attribute__((ext_vector_type(2))) _Float16 f16x2;
typedef __attribute__((ext_vector_type(4))) float f32x4;

#if __has_builtin(__builtin_amdgcn_fdot2)
#define HAS_FDOT2 1
#endif

__device__ __forceinline__ unsigned short f2h(float f) {
    return __builtin_bit_cast(unsigned short, (_Float16)f);
}
__device__ __forceinline__ f16x2 u2h2(unsigned u) {
    return __builtin_bit_cast(f16x2, u);
}
__device__ __forceinline__ float h2f_lo(unsigned u) {
    return (float)__builtin_bit_cast(_Float16, (unsigned short)(u & 0xffffu));
}
__device__ __forceinline__ float h2f_hi(unsigned u) {
    return (float)__builtin_bit_cast(_Float16, (unsigned short)(u >> 16));
}
// dot of packed f16 pairs with fp32 accumulate
__device__ __forceinline__ float dot2h(unsigned a, unsigned b, float c) {
#ifdef HAS_FDOT2
    return __builtin_amdgcn_fdot2(u2h2(a), u2h2(b), c, false);
#else
    c = fmaf(h2f_lo(a), h2f_lo(b), c);
    return fmaf(h2f_hi(a), h2f_hi(b), c);
#endif
}

// async global->LDS DMA. LDS dest is wave-uniform base; HW adds lane*width.
__device__ __forceinline__ void gload_lds16(const void* gptr, void* lptr) {
    __builtin_amdgcn_global_load_lds(
        (const __attribute__((address_space(1))) unsigned int*)gptr,
        (__attribute__((address_space(3))) unsigned int*)lptr,
        16, 0, 0);
}

// ---------------- fp32 -> f16 converter (x + all weights, one launch) ----------------
__global__ __launch_bounds__(256) void cvt_all(
    const float* __restrict__ x,
    const float* __restrict__ Wq, const float* __restrict__ Wk,
    const float* __restrict__ Wv, const float* __restrict__ Wo,
    unsigned short* __restrict__ Xb, unsigned short* __restrict__ Wfb,
    unsigned short* __restrict__ Wob)
{
    const int blk = blockIdx.x;
    const float* src;
    unsigned short* dst;
    int off;
    if (blk < 8192) {
        off = (blk * 256 + threadIdx.x) * 4;
        src = x; dst = Xb;
    } else {
        const int e = ((blk - 8192) * 256 + threadIdx.x) * 4;   // over 4*262144
        const int t = e >> 18;
        off = e & 262143;
        src = (t == 0) ? Wq : (t == 1) ? Wk : (t == 2) ? Wv : Wo;
        dst = (t < 3) ? (Wfb + (size_t)t * 262144) : Wob;
    }
    const float4 v = *(const float4*)(src + off);
    ushort4 u;
    u.x = f2h(v.x); u.y = f2h(v.y); u.z = f2h(v.z); u.w = f2h(v.w);
    *(ushort4*)(dst + off) = u;
}

// ---------------- Kernel 1: fused QKV projection + LayerNorm, f16 MFMA ----------------
// r11 version verbatim: 2-phase dbuf + XCD swizzle + T2 source-preswizzle.
__global__ __launch_bounds__(256) void gemm_qkv(
    const unsigned short* __restrict__ Xb, const unsigned short* __restrict__ Wfb,
    unsigned short* __restrict__ Qh, unsigned short* __restrict__ Kh,
    unsigned short* __restrict__ Vh)
{
    __shared__ unsigned short Als[2][128 * 32];   // 16 KB
    __shared__ unsigned short Bls[2][128 * 32];   // 16 KB
    const int tid  = threadIdx.x;
    const int wave = tid >> 6, lane = tid & 63;
    const int wm = wave >> 1, wn = wave & 1;
    const int quad = lane >> 4, r = lane & 15;
    const int p = blockIdx.x;                 // 0..1535
    const int L = (p & 7) * 192 + (p >> 3);   // XCD-contiguous logical id
    const int row0 = (L / 12) * 128;
    const int c0   = (L % 12) * 128;          // 128 | 512 so tile is within one tensor

    f32x4 acc[4][4];
    #pragma unroll
    for (int i = 0; i < 4; ++i)
        #pragma unroll
        for (int j = 0; j < 4; ++j) acc[i][j] = (f32x4)0.f;

    const char* Ab = (const char*)Xb;
    const char* Bb = (const char*)Wfb;

    const int rr0  = wave * 16 + (lane >> 2);          // rows 0..63 half
    const int rr1  = 64 + rr0;                         // rows 64..127 half
    const int offS = ((lane & 3) ^ ((lane >> 3) & 3)) << 4;

    {
        gload_lds16(Ab + (size_t)(row0 + rr0) * 1024 + offS, (char*)Als[0] + (wave * 1024));
        gload_lds16(Bb + (size_t)(c0   + rr0) * 1024 + offS, (char*)Bls[0] + (wave * 1024));
        gload_lds16(Ab + (size_t)(row0 + rr1) * 1024 + offS, (char*)Als[0] + (4096 + wave * 1024));
        gload_lds16(Bb + (size_t)(c0   + rr1) * 1024 + offS, (char*)Bls[0] + (4096 + wave * 1024));
    }
    __syncthreads();    // drains vmcnt -> tile 0 resident

    const int swz = (r & 6) << 3;                      // read-side XOR (bytes)

    for (int kt = 0; kt < 16; ++kt) {
        const int cur = kt & 1;
        if (kt < 15) {   // stage tile kt+1 into the other buffer
            const int kb = (kt + 1) * 64;   // byte offset of K-slice
            gload_lds16(Ab + (size_t)(row0 + rr0) * 1024 + kb + offS, (char*)Als[cur ^ 1] + (wave * 1024));
            gload_lds16(Bb + (size_t)(c0   + rr0) * 1024 + kb + offS, (char*)Bls[cur ^ 1] + (wave * 1024));
            gload_lds16(Ab + (size_t)(row0 + rr1) * 1024 + kb + offS, (char*)Als[cur ^ 1] + (4096 + wave * 1024));
            gload_lds16(Bb + (size_t)(c0   + rr1) * 1024 + kb + offS, (char*)Bls[cur ^ 1] + (4096 + wave * 1024));
        }

        f16x8 af[4], bf[4];
        #pragma unroll
        for (int i = 0; i < 4; ++i)
            af[i] = *(const f16x8*)((const char*)Als[cur] + (wm * 64 + i * 16 + r) * 64 + (quad * 16 ^ swz));
        #pragma unroll
        for (int j = 0; j < 4; ++j)
            bf[j] = *(const f16x8*)((const char*)Bls[cur] + (wn * 64 + j * 16 + r) * 64 + (quad * 16 ^ swz));
        #pragma unroll
        for (int i = 0; i < 4; ++i)
            #pragma unroll
            for (int j = 0; j < 4; ++j)
                acc[i][j] = __builtin_amdgcn_mfma_f32_16x16x32_f16(af[i], bf[j], acc[i][j], 0, 0, 0);

        __syncthreads();   // staged loads landed (vmcnt drain) + buffer handoff
    }

    const int tensor = c0 >> 9;   // block-uniform: 0=Q 1=K 2=V
    unsigned short* OutH = (tensor == 0) ? Qh : (tensor == 1) ? Kh : Vh;

    float mu[4][4], rs[4][4];
    if (tensor < 2) {
        #pragma unroll
        for (int i = 0; i < 4; ++i) {
            #pragma unroll
            for (int reg = 0; reg < 4; ++reg) {
                float sm = acc[i][0][reg] + acc[i][1][reg] + acc[i][2][reg] + acc[i][3][reg];
                sm += __shfl_xor(sm, 1); sm += __shfl_xor(sm, 2);
                sm += __shfl_xor(sm, 4); sm += __shfl_xor(sm, 8);
                const float muv = sm * (1.f / 64.f);
                float qv = 0.f;
                #pragma unroll
                for (int j = 0; j < 4; ++j) {
                    const float dv = acc[i][j][reg] - muv;
                    qv = fmaf(dv, dv, qv);
                }
                qv += __shfl_xor(qv, 1); qv += __shfl_xor(qv, 2);
                qv += __shfl_xor(qv, 4); qv += __shfl_xor(qv, 8);
                mu[i][reg] = muv;
                rs[i][reg] = rsqrtf(qv * (1.f / 64.f) + 1e-5f);
            }
        }
    }

    // C/D layout col=lane&15, row=quad*4+reg (verified m89).
    #pragma unroll
    for (int i = 0; i < 4; ++i) {
        #pragma unroll
        for (int j = 0; j < 4; ++j) {
            const int cc = (c0 & 511) + wn * 64 + j * 16 + r;
            const int h = cc >> 6, d = cc & 63;
            #pragma unroll
            for (int reg = 0; reg < 4; ++reg) {
                const int row = row0 + wm * 64 + i * 16 + quad * 4 + reg;
                const int b = row >> 13, n = row & 8191;
                float v = acc[i][j][reg];
                if (tensor < 2) v = (v - mu[i][reg]) * rs[i][reg];
                OutH[(((size_t)(b * HH + h) * NN + n) << 6) + d] = f2h(v);
            }
        }
    }
}

// ---------------- Kernel 2: gather-attention, 2 tasks per wave ----------------
// Round-13 change (ONLY change): each wave processes TWO consecutive tasks
// (n0, n0+1; same bh) with fully independent register state, phases
// interleaved. Doubles in-flight gather loads per wave -- the direct test of
// the r8 MLP-bound finding in the winning direction. No LDS, no waitcnt
// pinning (r3's failure modes), no reduction in per-task load count.
// r12 lesson: occupancy (~66%) is invariant to launch shape -- per-wave MLP
// is the remaining lever. VGPR cap 128 via __launch_bounds__(256,4).
// Mapping: p in [0,16384): L = ((p&7)<<11)|(p>>3); wid0 = L*8 + wave*2
// (bijective over 0..131071; n0 even so n0+1 stays in the same bh slab).
__global__ __launch_bounds__(256, 4) void attn(
    const unsigned short* __restrict__ Qh, const unsigned short* __restrict__ Kh,
    const unsigned short* __restrict__ Vh,
    const int* __restrict__ idx, unsigned short* __restrict__ Ob)
{
    const int p = blockIdx.x;                       // 0..16383
    const int L = ((p & 7) << 11) | (p >> 3);       // XCD-contiguous logical id
    const int wave = threadIdx.x >> 6;
    const int wid0 = L * 8 + wave * 2;              // tasks wid0, wid0+1
    const int lane = threadIdx.x & 63;
    const int bh = wid0 >> 13;
    const int n0 = wid0 & 8191;                     // even; n1 = n0+1 same bh
    const size_t base = (size_t)bh * NN * DK;       // element offset of (b,h) slab

    // canonical neighbor layouts for both tasks
    const int ga0 = idx[n0 * KNB + (lane & 31)];
    const int ga1 = idx[(n0 + 1) * KNB + (lane & 31)];

    const int k    = lane >> 1;
    const int half = lane & 1;
    const int g0 = __builtin_amdgcn_ds_bpermute(k * 4, ga0);
    const int g1 = __builtin_amdgcn_ds_bpermute(k * 4, ga1);

    const uint4* q40 = (const uint4*)(Qh + base + ((size_t)n0 << 6) + half * 32);
    const uint4* q41 = (const uint4*)(Qh + base + ((size_t)(n0 + 1) << 6) + half * 32);
    const uint4* k40 = (const uint4*)(Kh + base + ((size_t)g0 << 6) + half * 32);
    const uint4* k41 = (const uint4*)(Kh + base + ((size_t)g1 << 6) + half * 32);

    // Score, both tasks interleaved (2 chains each).
    float a00 = 0.f, a01 = 0.f, a10 = 0.f, a11 = 0.f;
    #pragma unroll
    for (int c = 0; c < 4; ++c) {
        const uint4 qa0 = q40[c], ka0 = k40[c];
        const uint4 qa1 = q41[c], ka1 = k41[c];
        if ((c & 1) == 0) {
            a00 = dot2h(qa0.x, ka0.x, a00); a00 = dot2h(qa0.y, ka0.y, a00);
            a00 = dot2h(qa0.z, ka0.z, a00); a00 = dot2h(qa0.w, ka0.w, a00);
            a10 = dot2h(qa1.x, ka1.x, a10); a10 = dot2h(qa1.y, ka1.y, a10);
            a10 = dot2h(qa1.z, ka1.z, a10); a10 = dot2h(qa1.w, ka1.w, a10);
        } else {
            a01 = dot2h(qa0.x, ka0.x, a01); a01 = dot2h(qa0.y, ka0.y, a01);
            a01 = dot2h(qa0.z, ka0.z, a01); a01 = dot2h(qa0.w, ka0.w, a01);
            a11 = dot2h(qa1.x, ka1.x, a11); a11 = dot2h(qa1.y, ka1.y, a11);
            a11 = dot2h(qa1.z, ka1.z, a11); a11 = dot2h(qa1.w, ka1.w, a11);
        }
    }
    const float acc0 = a00 + a01;
    const float acc1 = a10 + a11;
    const float s0 = (acc0 + __shfl_xor(acc0, 1)) * 0.125f;   // 1/sqrt(64)
    const float s1 = (acc1 + __shfl_xor(acc1, 1)) * 0.125f;

    // softmax (no max subtraction: |s| <= ~8.03 on LN'd rows, f32-safe)
    const float e0 = __expf(s0);
    const float e1 = __expf(s1);
    float t0s = e0, t1s = e1;
    #pragma unroll
    for (int off = 2; off <= 32; off <<= 1) {
        t0s += __shfl_xor(t0s, off);
        t1s += __shfl_xor(t1s, off);
    }
    const float pr0 = e0 / t0s;
    const float pr1 = e1 / t1s;

    // Pack p pairs (f16): lane 4j holds p_{2j} | p_{2j+1}<<16.
    const unsigned prh0 = (unsigned)f2h(pr0);
    const unsigned prh1 = (unsigned)f2h(pr1);
    const unsigned pp0 = prh0 | (((unsigned)__shfl_xor((int)prh0, 2)) << 16);
    const unsigned pp1 = prh1 | (((unsigned)__shfl_xor((int)prh1, 2)) << 16);

    // PV, both tasks interleaved: 4 concurrent V loads per iteration.
    const char* Vbytes = (const char*)Vh + (base << 1);
    const int c2 = lane & 31, h2 = lane >> 5;
    float o00 = 0.f, o01 = 0.f, o10 = 0.f, o11 = 0.f;
    #pragma unroll
    for (int j = 0; j < 8; ++j) {
        const int e0a = (h2 * 16 + 2 * j) * 4, e1a = e0a + 4;
        const int r00 = __builtin_amdgcn_ds_bpermute(e0a, ga0);
        const int r01 = __builtin_amdgcn_ds_bpermute(e1a, ga0);
        const int r10 = __builtin_amdgcn_ds_bpermute(e0a, ga1);
        const int r11 = __builtin_amdgcn_ds_bpermute(e1a, ga1);
        const unsigned vx0 = *(const unsigned*)(Vbytes + (size_t)(r00 * 128) + c2 * 4);
        const unsigned vy0 = *(const unsigned*)(Vbytes + (size_t)(r01 * 128) + c2 * 4);
        const unsigned vx1 = *(const unsigned*)(Vbytes + (size_t)(r10 * 128) + c2 * 4);
        const unsigned vy1 = *(const unsigned*)(Vbytes + (size_t)(r11 * 128) + c2 * 4);
        const unsigned pj0 = (unsigned)__builtin_amdgcn_ds_bpermute(h2 * 128 + j * 16, (int)pp0);
        const unsigned pj1 = (unsigned)__builtin_amdgcn_ds_bpermute(h2 * 128 + j * 16, (int)pp1);
        const unsigned u00 = __builtin_amdgcn_perm(vx0, vy0, 0x01000504u);
        const unsigned u01 = __builtin_amdgcn_perm(vx0, vy0, 0x03020706u);
        const unsigned u10 = __builtin_amdgcn_perm(vx1, vy1, 0x01000504u);
        const unsigned u11 = __builtin_amdgcn_perm(vx1, vy1, 0x03020706u);
        o00 = dot2h(u00, pj0, o00);   // task0, dim 2c
        o01 = dot2h(u01, pj0, o01);   // task0, dim 2c+1
        o10 = dot2h(u10, pj1, o10);   // task1, dim 2c
        o11 = dot2h(u11, pj1, o11);   // task1, dim 2c+1
    }
    o00 += __shfl_xor(o00, 32); o01 += __shfl_xor(o01, 32);
    o10 += __shfl_xor(o10, 32); o11 += __shfl_xor(o11, 32);
    if (lane < 32) {
        const int b = bh >> 3, hh = bh & 7;
        const unsigned ov0 = (unsigned)f2h(o00) | ((unsigned)f2h(o01) << 16);
        const unsigned ov1 = (unsigned)f2h(o10) | ((unsigned)f2h(o11) << 16);
        unsigned short* obase = Ob + ((size_t)(b * NN + n0)) * DD + hh * DK + 2 * c2;
        *(unsigned*)obase = ov0;
        *(unsigned*)(obase + DD) = ov1;     // n0+1 row is DD elements later
    }
}

// ---------------- Kernel 3: output projection, f16 MFMA ----------------
// r11 version verbatim (2-phase + XCD swizzle + T2 preswizzle).
__global__ __launch_bounds__(256) void gemm_out(
    const unsigned short* __restrict__ Ob, const unsigned short* __restrict__ Wob,
    const float* __restrict__ bout, float* __restrict__ out)
{
    __shared__ unsigned short Als[2][128 * 32];
    __shared__ unsigned short Bls[2][128 * 32];
    const int tid  = threadIdx.x;
    const int wave = tid >> 6, lane = tid & 63;
    const int wm = wave >> 1, wn = wave & 1;
    const int quad = lane >> 4, r = lane & 15;
    const int p = blockIdx.x;                 // 0..511
    const int L = (p & 7) * 64 + (p >> 3);    // XCD-contiguous logical id
    const int row0 = (L >> 2) * 128;
    const int c0   = (L & 3) * 128;

    f32x4 acc[4][4];
    #pragma unroll
    for (int i = 0; i < 4; ++i)
        #pragma unroll
        for (int j = 0; j < 4; ++j) acc[i][j] = (f32x4)0.f;

    const char* Ab = (const char*)Ob;
    const char* Bb = (const char*)Wob;

    const int rr0  = wave * 16 + (lane >> 2);
    const int rr1  = 64 + rr0;
    const int offS = ((lane & 3) ^ ((lane >> 3) & 3)) << 4;

    {
        gload_lds16(Ab + (size_t)(row0 + rr0) * 1024 + offS, (char*)Als[0] + (wave * 1024));
        gload_lds16(Bb + (size_t)(c0   + rr0) * 1024 + offS, (char*)Bls[0] + (wave * 1024));
        gload_lds16(Ab + (size_t)(row0 + rr1) * 1024 + offS, (char*)Als[0] + (4096 + wave * 1024));
        gload_lds16(Bb + (size_t)(c0   + rr1) * 1024 + offS, (char*)Bls[0] + (4096 + wave * 1024));
    }
    __syncthreads();

    const int swz = (r & 6) << 3;

    for (int kt = 0; kt < 16; ++kt) {
        const int cur = kt & 1;
        if (kt < 15) {
            const int kb = (kt + 1) * 64;
            gload_lds16(Ab + (size_t)(row0 + rr0) * 1024 + kb + offS, (char*)Als[cur ^ 1] + (wave * 1024));
            gload_lds16(Bb + (size_t)(c0   + rr0) * 1024 + kb + offS, (char*)Bls[cur ^ 1] + (wave * 1024));
            gload_lds16(Ab + (size_t)(row0 + rr1) * 1024 + kb + offS, (char*)Als[cur ^ 1] + (4096 + wave * 1024));
            gload_lds16(Bb + (size_t)(c0   + rr1) * 1024 + kb + offS, (char*)Bls[cur ^ 1] + (4096 + wave * 1024));
        }

        f16x8 af[4], bf[4];
        #pragma unroll
        for (int i = 0; i < 4; ++i)
            af[i] = *(const f16x8*)((const char*)Als[cur] + (wm * 64 + i * 16 + r) * 64 + (quad * 16 ^ swz));
        #pragma unroll
        for (int j = 0; j < 4; ++j)
            bf[j] = *(const f16x8*)((const char*)Bls[cur] + (wn * 64 + j * 16 + r) * 64 + (quad * 16 ^ swz));
        #pragma unroll
        for (int i = 0; i < 4; ++i)
            #pragma unroll
            for (int j = 0; j < 4; ++j)
                acc[i][j] = __builtin_amdgcn_mfma_f32_16x16x32_f16(af[i], bf[j], acc[i][j], 0, 0, 0);

        __syncthreads();
    }

    #pragma unroll
    for (int i = 0; i < 4; ++i) {
        #pragma unroll
        for (int j = 0; j < 4; ++j) {
            const int colg = c0 + wn * 64 + j * 16 + r;
            const float bb = bout[colg];
            #pragma unroll
            for (int reg = 0; reg < 4; ++reg) {
                const int row = row0 + wm * 64 + i * 16 + quad * 4 + reg;
                out[((size_t)row << 9) + colg] = acc[i][j][reg] + bb;
            }
        }
    }
}

extern "C" void kernel_launch(void* const* d_in, const int* in_sizes, int n_in,
                              void* d_out, int out_size, void* d_ws, size_t ws_size,
                              hipStream_t stream)
{
    const float* x    = (const float*)d_in[0];
    const int*   idx  = (const int*)  d_in[1];
    const float* Wq   = (const float*)d_in[2];
    const float* Wk   = (const float*)d_in[3];
    const float* Wv   = (const float*)d_in[4];
    const float* Wout = (const float*)d_in[5];
    const float* bout = (const float*)d_in[6];

    char* ws = (char*)d_ws;
    unsigned short* Qh  = (unsigned short*)(ws);              // 16777216 B
    unsigned short* Kh  = (unsigned short*)(ws + 16777216);   // 16777216 B
    unsigned short* Vh  = (unsigned short*)(ws + 33554432);   // 16777216 B
    unsigned short* Xb  = (unsigned short*)(ws + 50331648);   // 16777216 B; aliased as Ob
    unsigned short* Ob  = Xb;
    unsigned short* Wfb = (unsigned short*)(ws + 67108864);   // 1572864 B (Wq|Wk|Wv rows)
    unsigned short* Wob = (unsigned short*)(ws + 68681728);   // 524288 B
    float* out = (float*)d_out;

    cvt_all<<<9216, 256, 0, stream>>>(x, Wq, Wk, Wv, Wout, Xb, Wfb, Wob);

    gemm_qkv<<<1536, 256, 0, stream>>>(Xb, Wfb, Qh, Kh, Vh);   // 128 row-tiles x 12 col-tiles, XCD-swizzled

    attn<<<BHN / 8, 256, 0, stream>>>(Qh, Kh, Vh, idx, Ob);    // 16384 blocks: 4 waves x 2 tasks

    gemm_out<<<512, 256, 0, stream>>>(Ob, Wob, bout, out);     // 128 row-tiles x 4 col-tiles, XCD-swizzled
}